// Round 2
// baseline (124.726 us; speedup 1.0000x reference)
//
#include <hip/hip_runtime.h>
#include <math.h>

#define NBINS 10
#define NTH 9

// loss = (1/n_nonempty) * sum_b S_b / cnt_b   (tot cancels; weight is 0/1)
// With t in {0,1}: x = (1-2t)*p;  g = sigmoid(x);  bce = softplus(x).
// bin(g) boundaries k/10  <=>  x thresholds logit(k/10).
// Accumulate cumulative T_k = sum[x>=th_k] bce*w (VALU: cmp+cndmask+add)
// and C_k = count[x>=th_k & valid] via ballot+popc (scalar pipe).

__global__ __launch_bounds__(256) void ghmc_partials(
    const float* __restrict__ pred,
    const int*   __restrict__ target,
    const float* __restrict__ weight,
    float*        __restrict__ ws_sum,   // [NBINS * NB]
    unsigned int* __restrict__ ws_cnt,   // [NBINS * NB]
    long long n, int NB)
{
  // logit(k/10), k=1..9
  const float th[NTH] = { -2.1972246f, -1.3862944f, -0.84729786f, -0.40546511f,
                           0.0f,
                           0.40546511f, 0.84729786f, 1.3862944f,  2.1972246f };

  float        T[NBINS];   // T[0] = total gated bce; T[k] = sum where x>=th[k-1]
  unsigned int C[NBINS];   // wave-uniform: C[0] = valid count; C[k] = cnt x>=th[k-1]
#pragma unroll
  for (int b = 0; b < NBINS; b++) { T[b] = 0.0f; C[b] = 0u; }

  const long long nv4    = n >> 2;
  const long long stride = (long long)gridDim.x * blockDim.x;
  long long idx = (long long)blockIdx.x * blockDim.x + threadIdx.x;

  const float4* p4 = (const float4*)pred;
  const int4*   t4 = (const int4*)target;
  const float4* w4 = (const float4*)weight;

  auto proc = [&](float pj, int tj, float wj) {
    float x     = (tj != 0) ? -pj : pj;
    bool  valid = wj > 0.0f;
    float xg    = valid ? x : -3.0e30f;            // fails every threshold
    float q     = __expf(-fabsf(x));               // exp(-|x|), (0,1]
    float bce   = fmaxf(x, 0.0f) + __logf(1.0f + q);  // softplus(x)
    bce *= wj;                                     // gate sums (w is 0/1)
    T[0] += bce;
    C[0] += (unsigned)__popcll(__ballot(valid));
#pragma unroll
    for (int k = 0; k < NTH; k++) {
      bool c = xg >= th[k];
      C[k + 1] += (unsigned)__popcll(__ballot(c)); // SALU: bcnt+add
      T[k + 1] += c ? bce : 0.0f;                  // VALU: cndmask+add (cmp shared)
    }
  };

  auto body = [&](long long i) {
    float4 p = p4[i];
    int4   t = t4[i];
    float4 w = w4[i];
#pragma unroll
    for (int j = 0; j < 4; j++)
      proc((&p.x)[j], (&t.x)[j], (&w.x)[j]);
  };

  // 2x-unrolled grid-stride loop: 6 independent 16B loads in flight
  long long i = idx;
  for (; i + stride < nv4; i += 2 * stride) {
    body(i);
    body(i + stride);
  }
  if (i < nv4) body(i);

  // scalar tail (n % 4) by global thread 0 (zero iters for this shape)
  if (idx == 0) {
    for (long long e = (nv4 << 2); e < n; e++)
      proc(pred[e], target[e], weight[e]);
  }

  // cumulative -> per-bin (small magnitudes; no cancellation downstream)
  float        S[NBINS];
  unsigned int cnt[NBINS];
#pragma unroll
  for (int b = 0; b < NBINS; b++) {
    float        tn = (b + 1 < NBINS) ? T[b + 1] : 0.0f;
    unsigned int cn = (b + 1 < NBINS) ? C[b + 1] : 0u;
    S[b]   = T[b] - tn;
    cnt[b] = C[b] - cn;
  }

  // wave-reduce sums (counts are already per-wave via ballot; lane 0 holds
  // the complete value since lane 0 has the smallest idx -> most iterations)
  int lane = threadIdx.x & 63, wid = threadIdx.x >> 6;
#pragma unroll
  for (int b = 0; b < NBINS; b++) {
    float v = S[b];
    for (int off = 32; off >= 1; off >>= 1) v += __shfl_down(v, off);
    S[b] = v;
  }

  __shared__ float        ls[NBINS][4];
  __shared__ unsigned int lc[NBINS][4];
  if (lane == 0) {
#pragma unroll
    for (int b = 0; b < NBINS; b++) { ls[b][wid] = S[b]; lc[b][wid] = cnt[b]; }
  }
  __syncthreads();
  if (threadIdx.x < NBINS) {
    int b = threadIdx.x;
    float        s = ls[b][0] + ls[b][1] + ls[b][2] + ls[b][3];
    unsigned int c = lc[b][0] + lc[b][1] + lc[b][2] + lc[b][3];
    ws_sum[b * NB + blockIdx.x] = s;
    ws_cnt[b * NB + blockIdx.x] = c;
  }
}

__global__ __launch_bounds__(256) void ghmc_finalize(
    const float*        __restrict__ ws_sum,
    const unsigned int* __restrict__ ws_cnt,
    float* __restrict__ out, int NB)
{
  double    ds[NBINS];
  long long dc[NBINS];
#pragma unroll
  for (int b = 0; b < NBINS; b++) { ds[b] = 0.0; dc[b] = 0; }

  for (int i = threadIdx.x; i < NB; i += 256) {
#pragma unroll
    for (int b = 0; b < NBINS; b++) {
      ds[b] += (double)ws_sum[b * NB + i];
      dc[b] += (long long)ws_cnt[b * NB + i];
    }
  }

  __shared__ double    ssum[NBINS][4];
  __shared__ long long scnt[NBINS][4];
  int lane = threadIdx.x & 63, wid = threadIdx.x >> 6;
#pragma unroll
  for (int b = 0; b < NBINS; b++) {
    double    v = ds[b];
    long long c = dc[b];
    for (int off = 32; off >= 1; off >>= 1) {
      v += __shfl_down(v, off);
      c += __shfl_down(c, off);
    }
    if (lane == 0) { ssum[b][wid] = v; scnt[b][wid] = c; }
  }
  __syncthreads();

  if (threadIdx.x == 0) {
    int n_ne = 0;
    double sums[NBINS];
    long long cnts[NBINS];
#pragma unroll
    for (int b = 0; b < NBINS; b++) {
      double v = 0.0; long long c = 0;
      for (int w = 0; w < 4; w++) { v += ssum[b][w]; c += scnt[b][w]; }
      sums[b] = v; cnts[b] = c;
      n_ne += (c > 0) ? 1 : 0;
    }
    double nne  = (n_ne > 0) ? (double)n_ne : 1.0;
    double loss = 0.0;
#pragma unroll
    for (int b = 0; b < NBINS; b++) {
      if (cnts[b] > 0) loss += sums[b] / ((double)cnts[b] * nne);
    }
    out[0] = (float)loss;  // LOSS_WEIGHT = 1.0
  }
}

extern "C" void kernel_launch(void* const* d_in, const int* in_sizes, int n_in,
                              void* d_out, int out_size, void* d_ws, size_t ws_size,
                              hipStream_t stream)
{
  const float* pred   = (const float*)d_in[0];
  const int*   target = (const int*)d_in[1];
  const float* weight = (const float*)d_in[2];
  float* out = (float*)d_out;
  long long n = (long long)in_sizes[0];

  int NB = 2048;
  size_t per_block = (size_t)NBINS * (sizeof(float) + sizeof(unsigned int));
  if (ws_size < (size_t)NB * per_block) {
    int maxnb = (int)(ws_size / per_block);
    NB = (maxnb < 1) ? 1 : maxnb;
  }
  float*        ws_sum = (float*)d_ws;
  unsigned int* ws_cnt = (unsigned int*)((char*)d_ws + (size_t)NBINS * NB * sizeof(float));

  ghmc_partials<<<NB, 256, 0, stream>>>(pred, target, weight, ws_sum, ws_cnt, n, NB);
  ghmc_finalize<<<1, 256, 0, stream>>>(ws_sum, ws_cnt, out, NB);
}